// Round 3
// baseline (9349.052 us; speedup 1.0000x reference)
//
#include <hip/hip_runtime.h>
#include <hip/hip_bf16.h>

// LSTM forward, MI355X. B=128, T=512, F=256, H=512. Gates order: i,f,c,o.
// Phase 0: convert x->bf16, W/U -> transposed bf16 [n][k].
// Phase 1: Gx[t][g][b][h] = x@W_g + b_g  (bf16 MFMA, fp32 acc, bf16 store).
// Phase 2: persistent recurrence, 64 blocks = 2 independent groups of 32
//          (group owns 64 batch rows; block owns 16 h-cols), U slice LDS-resident,
//          c in regs, h double-buffered in ws, per-step group barrier
//          (agent-scope release/acquire flags). Spin sits at iteration top so
//          gpre prefetch overlaps it; out[] stores happen after flag release.
// R2 fix: phase-1 LDS staging granule id was q*1024+tid (OOB, clobbered ldsB /
//          left rows 32..127 stale) -> q*256+tid. 128x64 tile = 1024 granules.

typedef __attribute__((ext_vector_type(8))) short bf16x8;
typedef __attribute__((ext_vector_type(4))) short s16x4;
typedef __attribute__((ext_vector_type(4))) float f32x4;

#define DEVI static __device__ __forceinline__

DEVI short f2bf(float x) {
  unsigned u = __builtin_bit_cast(unsigned, x);
  unsigned r = (u + 0x7fffu + ((u >> 16) & 1u)) >> 16;  // RNE
  return (short)r;
}
DEVI float bf2f(short s) {
  unsigned u = ((unsigned)(unsigned short)s) << 16;
  return __builtin_bit_cast(float, u);
}

// ---------------- phase 0: conversions ----------------
__global__ __launch_bounds__(256) void k_cvt_x(const float* __restrict__ x,
                                               short* __restrict__ xb) {
  int i = blockIdx.x * 256 + threadIdx.x;   // 4 elems each; grid covers exactly 16,777,216
  float4 v = reinterpret_cast<const float4*>(x)[i];
  s16x4 o;
  o.x = f2bf(v.x); o.y = f2bf(v.y); o.z = f2bf(v.z); o.w = f2bf(v.w);
  reinterpret_cast<s16x4*>(xb)[i] = o;
}

__global__ __launch_bounds__(256) void k_cvt_wu(
    const float* __restrict__ w0, const float* __restrict__ w1,
    const float* __restrict__ w2, const float* __restrict__ w3,
    const float* __restrict__ u0, const float* __restrict__ u1,
    const float* __restrict__ u2, const float* __restrict__ u3,
    short* __restrict__ wt, short* __restrict__ ut) {
  int s = blockIdx.y;
  int i = blockIdx.x * 256 + threadIdx.x;
  if (s < 4) {                       // W_s: (256 k x 512 n) -> wt[s][n][k]
    if (i < 512 * 256) {
      const float* w = s == 0 ? w0 : s == 1 ? w1 : s == 2 ? w2 : w3;
      wt[s * 131072 + i] = f2bf(w[(i & 255) * 512 + (i >> 8)]);
    }
  } else {                           // U_g: (512 k x 512 n) -> ut[g][n][k]
    const float* u = s == 4 ? u0 : s == 5 ? u1 : s == 6 ? u2 : u3;
    ut[(s - 4) * 262144 + i] = f2bf(u[(i & 511) * 512 + (i >> 9)]);
  }
}

// ---------------- phase 1: Gx = x @ W + b ----------------
__global__ __launch_bounds__(256) void k_gemm_x(
    const short* __restrict__ xb,   // [65536][256] bf16, row m = b*512 + t
    const short* __restrict__ wt,   // [2048][256] bf16, row n = g*512 + h
    const float* __restrict__ bi, const float* __restrict__ bff,
    const float* __restrict__ bc, const float* __restrict__ bo,
    short* __restrict__ gx) {       // [512][4][128][512] bf16
  __shared__ short ldsA[128 * 64];
  __shared__ short ldsB[128 * 64];
  const int tid = threadIdx.x;
  const int lane = tid & 63;
  const int w = tid >> 6, wm = w >> 1, wn = w & 1;
  const int Mb = (int)(blockIdx.x >> 4) * 128;
  const int Nb = (int)(blockIdx.x & 15) * 128;
  f32x4 acc[4][4] = {};
  for (int k0 = 0; k0 < 256; k0 += 64) {
#pragma unroll
    for (int q = 0; q < 4; ++q) {   // stage 128x64 A and B tiles, XOR-swizzled
      int gi = q * 256 + tid;       // 1024 granules of 16B (R2 fix: was q*1024)
      int row = gi >> 3, gc = gi & 7;
      bf16x8 va = *reinterpret_cast<const bf16x8*>(xb + (size_t)(Mb + row) * 256 + k0 + gc * 8);
      int off = (row * 128 + gc * 16) ^ ((row & 7) << 4);
      *reinterpret_cast<bf16x8*>(reinterpret_cast<char*>(ldsA) + off) = va;
      bf16x8 vb = *reinterpret_cast<const bf16x8*>(wt + (size_t)(Nb + row) * 256 + k0 + gc * 8);
      *reinterpret_cast<bf16x8*>(reinterpret_cast<char*>(ldsB) + off) = vb;
    }
    __syncthreads();
#pragma unroll
    for (int kk = 0; kk < 2; ++kk) {
      const int kby = kk * 64 + (lane >> 4) * 16;   // byte offset of lane's 8 bf16
      bf16x8 af[4], bfr[4];
#pragma unroll
      for (int mf = 0; mf < 4; ++mf) {
        int row = wm * 64 + mf * 16 + (lane & 15);
        int off = (row * 128 + kby) ^ ((row & 7) << 4);
        af[mf] = *reinterpret_cast<const bf16x8*>(reinterpret_cast<const char*>(ldsA) + off);
      }
#pragma unroll
      for (int nf = 0; nf < 4; ++nf) {
        int row = wn * 64 + nf * 16 + (lane & 15);
        int off = (row * 128 + kby) ^ ((row & 7) << 4);
        bfr[nf] = *reinterpret_cast<const bf16x8*>(reinterpret_cast<const char*>(ldsB) + off);
      }
#pragma unroll
      for (int mf = 0; mf < 4; ++mf)
#pragma unroll
        for (int nf = 0; nf < 4; ++nf)
          acc[mf][nf] = __builtin_amdgcn_mfma_f32_16x16x32_bf16(af[mf], bfr[nf], acc[mf][nf], 0, 0, 0);
    }
    __syncthreads();
  }
  // epilogue: C/D layout col=lane&15, row=(lane>>4)*4+r  [m89-verified]
#pragma unroll
  for (int nf = 0; nf < 4; ++nf) {
    int n = Nb + wn * 64 + nf * 16 + (lane & 15);
    int g = n >> 9, hc = n & 511;
    const float* bp = g == 0 ? bi : g == 1 ? bff : g == 2 ? bc : bo;
    float bias = bp[hc];
#pragma unroll
    for (int mf = 0; mf < 4; ++mf) {
#pragma unroll
      for (int r = 0; r < 4; ++r) {
        int m = Mb + wm * 64 + mf * 16 + (lane >> 4) * 4 + r;
        int b = m >> 9, t = m & 511;   // xb row m = b*512 + t
        gx[(((size_t)t * 4 + g) * 128 + b) * 512 + hc] = f2bf(acc[mf][nf][r] + bias);
      }
    }
  }
}

// ---------------- phase 2: persistent recurrence ----------------
__global__ __launch_bounds__(256, 1) void k_lstm(
    const short* __restrict__ ut,   // [2048][512] bf16, row n = g*512 + h
    const short* __restrict__ gx,   // [512][4][128][512] bf16
    short* __restrict__ hb,         // [2][128][512] bf16 (hb[0] pre-zeroed)
    int* __restrict__ flags,       // [64] (pre-zeroed)
    float* __restrict__ out) {      // [128][512][512]
  extern __shared__ char lds[];     // [0,64K): U slice; [64K,128K): h tile; XOR-swizzled
  char* uL = lds;
  char* hL = lds + 65536;
  const int tid = threadIdx.x;
  const int lane = tid & 63;
  const int w = tid >> 6;           // wave 0..3, owns 16 batch rows
  const int bid = blockIdx.x;
  const int grp = bid >> 5;         // batch-tile group 0..1 (closed sync group)
  const int hbase = (bid & 31) * 16;  // 16 h-cols per block
  const int bbase = grp * 64;
  const int hc = lane & 15;
  const int rbase = (lane >> 4) * 4;

  // stage U slice once: local row g*16+hcl <-> ut row g*512 + hbase + hcl
#pragma unroll
  for (int q = 0; q < 16; ++q) {
    int gi = q * 256 + tid;         // 4096 granules of 16B
    int row = gi >> 6, gc = gi & 63;
    bf16x8 v = *reinterpret_cast<const bf16x8*>(
        ut + ((size_t)(row >> 4) * 512 + hbase + (row & 15)) * 512 + gc * 8);
    int off = (row * 1024 + gc * 16) ^ ((row & 7) << 4);
    *reinterpret_cast<bf16x8*>(uL + off) = v;
  }
  float c_reg[4] = {0.f, 0.f, 0.f, 0.f};
  __syncthreads();

  for (int t = 0; t < 512; ++t) {
    // (a) prefetch this step's x-gate contributions (no cross-block dependency)
    float gpre[4][4];
#pragma unroll
    for (int g = 0; g < 4; ++g)
#pragma unroll
      for (int r = 0; r < 4; ++r) {
        int b = bbase + w * 16 + rbase + r;
        gpre[g][r] = bf2f(gx[(((size_t)t * 4 + g) * 128 + b) * 512 + hbase + hc]);
      }
    // (b) wait until every block in the group published h(t); overlaps (a)'s loads
    if (tid < 32) {
      while (__hip_atomic_load(&flags[grp * 32 + tid], __ATOMIC_ACQUIRE,
                               __HIP_MEMORY_SCOPE_AGENT) < t)
        __builtin_amdgcn_s_sleep(1);
    }
    __syncthreads();
    // (c) stage h(t) tile (64 rows x 512 k bf16), XOR-swizzled
    const short* hsrc = hb + (t & 1) * 65536;
#pragma unroll
    for (int q = 0; q < 16; ++q) {
      int gi = q * 256 + tid;
      int row = gi >> 6, gc = gi & 63;
      bf16x8 v = *reinterpret_cast<const bf16x8*>(hsrc + (size_t)(bbase + row) * 512 + gc * 8);
      int off = (row * 1024 + gc * 16) ^ ((row & 7) << 4);
      *reinterpret_cast<bf16x8*>(hL + off) = v;
    }
    __syncthreads();
    // (d) gates = h @ U : wave w does 16b x (4 gates x 16hc), K=512
    f32x4 acc[4] = {};
#pragma unroll
    for (int kk = 0; kk < 16; ++kk) {
      const int kby = kk * 64 + (lane >> 4) * 16;
      int arow = w * 16 + (lane & 15);
      int aoff = (arow * 1024 + kby) ^ ((arow & 7) << 4);
      bf16x8 a = *reinterpret_cast<const bf16x8*>(hL + aoff);
#pragma unroll
      for (int g = 0; g < 4; ++g) {
        int brow = g * 16 + (lane & 15);
        int boff = (brow * 1024 + kby) ^ ((brow & 7) << 4);
        bf16x8 bb = *reinterpret_cast<const bf16x8*>(uL + boff);
        acc[g] = __builtin_amdgcn_mfma_f32_16x16x32_bf16(a, bb, acc[g], 0, 0, 0);
      }
    }
    // (e) LSTM cell; lane owns (b = bbase+w*16+rbase+r, hbase+hc). C/D: col=lane&15,
    //     row=(lane>>4)*4+r.  Write h(t+1) first — it's the only cross-block data.
    float hv[4];
#pragma unroll
    for (int r = 0; r < 4; ++r) {
      float pi = acc[0][r] + gpre[0][r];
      float pf = acc[1][r] + gpre[1][r];
      float pc = acc[2][r] + gpre[2][r];
      float po = acc[3][r] + gpre[3][r];
      float ig = 1.f / (1.f + __expf(-pi));
      float fg = 1.f / (1.f + __expf(-pf));
      float og = 1.f / (1.f + __expf(-po));
      float cb = tanhf(pc);
      float cn = fg * c_reg[r] + ig * cb;
      c_reg[r] = cn;
      hv[r] = og * tanhf(cn);
      int b = bbase + w * 16 + rbase + r;
      hb[((t + 1) & 1) * 65536 + b * 512 + hbase + hc] = f2bf(hv[r]);
    }
    // (f) publish: fence + flag release (flag value t+1 == "h(t+1) ready")
    __threadfence();
    __syncthreads();
    if (tid == 0)
      __hip_atomic_store(&flags[bid], t + 1, __ATOMIC_RELEASE, __HIP_MEMORY_SCOPE_AGENT);
    // (g) out stores AFTER the release — not on the inter-block critical path
#pragma unroll
    for (int r = 0; r < 4; ++r) {
      int b = bbase + w * 16 + rbase + r;
      out[(size_t)b * 262144 + (size_t)t * 512 + hbase + hc] = hv[r];
    }
  }
}

// ---------------- host ----------------
extern "C" void kernel_launch(void* const* d_in, const int* in_sizes, int n_in,
                              void* d_out, int out_size, void* d_ws, size_t ws_size,
                              hipStream_t stream) {
  const float* x = (const float*)d_in[0];
  const float* Wg[4] = {(const float*)d_in[1], (const float*)d_in[4],
                        (const float*)d_in[7], (const float*)d_in[10]};
  const float* Ug[4] = {(const float*)d_in[2], (const float*)d_in[5],
                        (const float*)d_in[8], (const float*)d_in[11]};
  const float* bg[4] = {(const float*)d_in[3], (const float*)d_in[6],
                        (const float*)d_in[9], (const float*)d_in[12]};
  float* out = (float*)d_out;
  char* ws = (char*)d_ws;

  // ws layout (all offsets 16B-aligned)
  int* flags = (int*)ws;                                   // 1 KB
  short* hb = (short*)(ws + 1024);                         // 256 KB (h double-buffer)
  short* xb = (short*)(ws + 263168);                       // 32 MB
  short* wt = (short*)(ws + 263168 + 33554432ull);         // 1 MB
  short* ut = (short*)(ws + 263168 + 33554432ull + 1048576ull);  // 2 MB
  const size_t base = 263168ull + 33554432ull + 1048576ull + 2097152ull;  // 36,963,328
  short* gx = (short*)(ws + base);                         // 256 MB bf16 Gx

  if (ws_size < base + 268435456ull) return;  // ws too small -> d_out stays poisoned (visible failure)

  hipMemsetAsync(ws, 0, 263168, stream);      // flags + h double-buffer
  k_cvt_x<<<16384, 256, 0, stream>>>(x, xb);
  k_cvt_wu<<<dim3(1024, 8), 256, 0, stream>>>(Wg[0], Wg[1], Wg[2], Wg[3],
                                              Ug[0], Ug[1], Ug[2], Ug[3], wt, ut);
  k_gemm_x<<<8192, 256, 0, stream>>>(xb, wt, bg[0], bg[1], bg[2], bg[3], gx);
  hipFuncSetAttribute(reinterpret_cast<const void*>(&k_lstm),
                      hipFuncAttributeMaxDynamicSharedMemorySize, 131072);
  k_lstm<<<64, 256, 131072, stream>>>(ut, gx, hb, flags, out);
}

// Round 4
// 6494.428 us; speedup vs baseline: 1.4395x; 1.4395x over previous
//
#include <hip/hip_runtime.h>
#include <hip/hip_bf16.h>

// LSTM forward, MI355X. B=128, T=512, F=256, H=512. Gates order: i,f,c,o.
// Phase 0: convert x->bf16, W/U -> transposed bf16 [n][k].
// Phase 1: Gx[t,...] = x@W_g + b_g (bf16 MFMA, fp32 acc, bf16 store) in the
//          block-contiguous layout E(t,b,hc,g) consumed by phase 2.
// Phase 2: persistent recurrence, 64 blocks = 2 independent groups of 32
//          (group owns 64 batch rows; block owns 16 h-cols). U slice LDS-resident;
//          h(t) loaded global->VGPR as MFMA A-fragments (no LDS staging);
//          c in regs; h double-buffered in ws.
//          Sync: per-group padded arrival counter; each WAVE does one
//          fetch_add(RELEASE, agent) after its h-stores (release orders the
//          wave's stores -> no threadfence); one lane per block polls
//          ctr >= 128*t (32 blocks x 4 waves). out[] stores after release.
// R2 fix: phase-1 staging granule id q*256+tid (was q*1024 OOB).
// R4: counter barrier (was 2048 pollers on one line + threadfence),
//     h->registers (was 64KB LDS round-trip/step), coalesced gpre layout.

typedef __attribute__((ext_vector_type(8))) short bf16x8;
typedef __attribute__((ext_vector_type(4))) short s16x4;
typedef __attribute__((ext_vector_type(4))) float f32x4;

#define DEVI static __device__ __forceinline__

DEVI short f2bf(float x) {
  unsigned u = __builtin_bit_cast(unsigned, x);
  unsigned r = (u + 0x7fffu + ((u >> 16) & 1u)) >> 16;  // RNE
  return (short)r;
}
DEVI float bf2f(short s) {
  unsigned u = ((unsigned)(unsigned short)s) << 16;
  return __builtin_bit_cast(float, u);
}

// Gx element index shared by producer (phase 1) and consumer (phase 2).
// bid = (b>>6)*32 + (hc>>4); w = (b>>4)&3; lane = ((b>>2)&3)*16 + (hc&15); r = b&3.
DEVI size_t gxE(int t, int b, int hc, int g) {
  return ((((size_t)t * 64 + (b >> 6) * 32 + (hc >> 4)) * 16 + g * 4 + ((b >> 4) & 3)) * 64 +
          ((b >> 2) & 3) * 16 + (hc & 15)) * 4 + (b & 3);
}

// ---------------- phase 0: conversions ----------------
__global__ __launch_bounds__(256) void k_cvt_x(const float* __restrict__ x,
                                               short* __restrict__ xb) {
  int i = blockIdx.x * 256 + threadIdx.x;   // 4 elems each; grid covers exactly 16,777,216
  float4 v = reinterpret_cast<const float4*>(x)[i];
  s16x4 o;
  o.x = f2bf(v.x); o.y = f2bf(v.y); o.z = f2bf(v.z); o.w = f2bf(v.w);
  reinterpret_cast<s16x4*>(xb)[i] = o;
}

__global__ __launch_bounds__(256) void k_cvt_wu(
    const float* __restrict__ w0, const float* __restrict__ w1,
    const float* __restrict__ w2, const float* __restrict__ w3,
    const float* __restrict__ u0, const float* __restrict__ u1,
    const float* __restrict__ u2, const float* __restrict__ u3,
    short* __restrict__ wt, short* __restrict__ ut) {
  int s = blockIdx.y;
  int i = blockIdx.x * 256 + threadIdx.x;
  if (s < 4) {                       // W_s: (256 k x 512 n) -> wt[s][n][k]
    if (i < 512 * 256) {
      const float* w = s == 0 ? w0 : s == 1 ? w1 : s == 2 ? w2 : w3;
      wt[s * 131072 + i] = f2bf(w[(i & 255) * 512 + (i >> 8)]);
    }
  } else {                           // U_g: (512 k x 512 n) -> ut[g][n][k]
    const float* u = s == 4 ? u0 : s == 5 ? u1 : s == 6 ? u2 : u3;
    ut[(s - 4) * 262144 + i] = f2bf(u[(i & 511) * 512 + (i >> 9)]);
  }
}

// ---------------- phase 1: Gx = x @ W + b ----------------
__global__ __launch_bounds__(256) void k_gemm_x(
    const short* __restrict__ xb,   // [65536][256] bf16, row m = b*512 + t
    const short* __restrict__ wt,   // [2048][256] bf16, row n = g*512 + h
    const float* __restrict__ bi, const float* __restrict__ bff,
    const float* __restrict__ bc, const float* __restrict__ bo,
    short* __restrict__ gx) {       // bf16, layout gxE
  __shared__ short ldsA[128 * 64];
  __shared__ short ldsB[128 * 64];
  const int tid = threadIdx.x;
  const int lane = tid & 63;
  const int w = tid >> 6, wm = w >> 1, wn = w & 1;
  const int Mb = (int)(blockIdx.x >> 4) * 128;
  const int Nb = (int)(blockIdx.x & 15) * 128;
  f32x4 acc[4][4] = {};
  for (int k0 = 0; k0 < 256; k0 += 64) {
#pragma unroll
    for (int q = 0; q < 4; ++q) {   // stage 128x64 A and B tiles, XOR-swizzled
      int gi = q * 256 + tid;       // 1024 granules of 16B
      int row = gi >> 3, gc = gi & 7;
      bf16x8 va = *reinterpret_cast<const bf16x8*>(xb + (size_t)(Mb + row) * 256 + k0 + gc * 8);
      int off = (row * 128 + gc * 16) ^ ((row & 7) << 4);
      *reinterpret_cast<bf16x8*>(reinterpret_cast<char*>(ldsA) + off) = va;
      bf16x8 vb = *reinterpret_cast<const bf16x8*>(wt + (size_t)(Nb + row) * 256 + k0 + gc * 8);
      *reinterpret_cast<bf16x8*>(reinterpret_cast<char*>(ldsB) + off) = vb;
    }
    __syncthreads();
#pragma unroll
    for (int kk = 0; kk < 2; ++kk) {
      const int kby = kk * 64 + (lane >> 4) * 16;   // byte offset of lane's 8 bf16
      bf16x8 af[4], bfr[4];
#pragma unroll
      for (int mf = 0; mf < 4; ++mf) {
        int row = wm * 64 + mf * 16 + (lane & 15);
        int off = (row * 128 + kby) ^ ((row & 7) << 4);
        af[mf] = *reinterpret_cast<const bf16x8*>(reinterpret_cast<const char*>(ldsA) + off);
      }
#pragma unroll
      for (int nf = 0; nf < 4; ++nf) {
        int row = wn * 64 + nf * 16 + (lane & 15);
        int off = (row * 128 + kby) ^ ((row & 7) << 4);
        bfr[nf] = *reinterpret_cast<const bf16x8*>(reinterpret_cast<const char*>(ldsB) + off);
      }
#pragma unroll
      for (int mf = 0; mf < 4; ++mf)
#pragma unroll
        for (int nf = 0; nf < 4; ++nf)
          acc[mf][nf] = __builtin_amdgcn_mfma_f32_16x16x32_bf16(af[mf], bfr[nf], acc[mf][nf], 0, 0, 0);
    }
    __syncthreads();
  }
  // epilogue: C/D layout col=lane&15, row=(lane>>4)*4+r  [m89-verified]
#pragma unroll
  for (int nf = 0; nf < 4; ++nf) {
    int n = Nb + wn * 64 + nf * 16 + (lane & 15);
    int g = n >> 9, hcg = n & 511;
    const float* bp = g == 0 ? bi : g == 1 ? bff : g == 2 ? bc : bo;
    float bias = bp[hcg];
#pragma unroll
    for (int mf = 0; mf < 4; ++mf) {
#pragma unroll
      for (int r = 0; r < 4; ++r) {
        int m = Mb + wm * 64 + mf * 16 + (lane >> 4) * 4 + r;
        int b = m >> 9, t = m & 511;   // xb row m = b*512 + t
        gx[gxE(t, b, hcg, g)] = f2bf(acc[mf][nf][r] + bias);
      }
    }
  }
}

// ---------------- phase 2: persistent recurrence ----------------
__global__ __launch_bounds__(256, 1) void k_lstm(
    const short* __restrict__ ut,   // [2048][512] bf16, row n = g*512 + h
    const short* __restrict__ gx,   // bf16, layout gxE
    short* __restrict__ hb,         // [2][128][512] bf16 (hb[0] pre-zeroed)
    int* __restrict__ ctr,          // group arrival counters @ byte 0 / 256 (pre-zeroed)
    float* __restrict__ out) {      // [128][512][512]
  extern __shared__ char lds[];     // 64 KB U slice, XOR-swizzled rows of 1024B
  char* uL = lds;
  const int tid = threadIdx.x;
  const int lane = tid & 63;
  const int w = tid >> 6;           // wave 0..3, owns 16 batch rows
  const int bid = blockIdx.x;
  const int grp = bid >> 5;         // batch-tile group 0..1 (closed sync group)
  const int hbase = (bid & 31) * 16;  // 16 h-cols per block
  const int bbase = grp * 64;
  const int hc = lane & 15;
  const int l4 = lane >> 4;
  const int rbase = l4 * 4;
  int* myctr = ctr + grp * 64;      // 256 B apart -> no false sharing

  // stage U slice once: local row g*16+hcl <-> ut row g*512 + hbase + hcl
#pragma unroll
  for (int q = 0; q < 16; ++q) {
    int gi = q * 256 + tid;         // 4096 granules of 16B
    int row = gi >> 6, gc = gi & 63;
    bf16x8 v = *reinterpret_cast<const bf16x8*>(
        ut + ((size_t)(row >> 4) * 512 + hbase + (row & 15)) * 512 + gc * 8);
    int off = (row * 1024 + gc * 16) ^ ((row & 7) << 4);
    *reinterpret_cast<bf16x8*>(uL + off) = v;
  }
  float c_reg[4] = {0.f, 0.f, 0.f, 0.f};
  __syncthreads();

  const int arow = bbase + w * 16 + (lane & 15);  // this lane's A-fragment row
  for (int t = 0; t < 512; ++t) {
    // (a) gpre: 4 coalesced b64 loads (wave reads 512B/gate); overlaps the spin
    s16x4 gp[4];
    {
      size_t e0 = ((((size_t)t * 64 + bid) * 16 + w) * 64 + l4 * 16 + hc) * 4;
#pragma unroll
      for (int g = 0; g < 4; ++g)
        gp[g] = *reinterpret_cast<const s16x4*>(gx + e0 + (size_t)g * 1024);
    }
    // (b) wait until all 128 waves of the group published h(t)
    if (tid == 0) {
      while (__hip_atomic_load(myctr, __ATOMIC_ACQUIRE, __HIP_MEMORY_SCOPE_AGENT) < 128 * t) {
      }
    }
    __syncthreads();
    // (c) h(t) A-fragments straight to VGPR: row=arow, k-elems kk*32 + l4*8
    const short* hsrc = hb + (t & 1) * 65536 + (size_t)arow * 512 + l4 * 8;
    bf16x8 af[16];
#pragma unroll
    for (int kk = 0; kk < 16; ++kk)
      af[kk] = *reinterpret_cast<const bf16x8*>(hsrc + kk * 32);
    // (d) gates = h @ U : wave w does 16b x (4 gates x 16hc), K=512
    f32x4 acc[4] = {};
#pragma unroll
    for (int kk = 0; kk < 16; ++kk) {
      const int kby = kk * 64 + l4 * 16;
#pragma unroll
      for (int g = 0; g < 4; ++g) {
        int brow = g * 16 + (lane & 15);
        int boff = (brow * 1024 + kby) ^ ((brow & 7) << 4);
        bf16x8 bb = *reinterpret_cast<const bf16x8*>(uL + boff);
        acc[g] = __builtin_amdgcn_mfma_f32_16x16x32_bf16(af[kk], bb, acc[g], 0, 0, 0);
      }
    }
    // (e) LSTM cell; lane owns (b = bbase+w*16+rbase+r, hbase+hc). C/D: col=lane&15,
    //     row=(lane>>4)*4+r. Write h(t+1) first — the only cross-block data.
    float hv[4];
#pragma unroll
    for (int r = 0; r < 4; ++r) {
      float pi = acc[0][r] + bf2f(gp[0][r]);
      float pf = acc[1][r] + bf2f(gp[1][r]);
      float pc = acc[2][r] + bf2f(gp[2][r]);
      float po = acc[3][r] + bf2f(gp[3][r]);
      float ig = 1.f / (1.f + __expf(-pi));
      float fg = 1.f / (1.f + __expf(-pf));
      float og = 1.f / (1.f + __expf(-po));
      float cb = tanhf(pc);
      float cn = fg * c_reg[r] + ig * cb;
      c_reg[r] = cn;
      hv[r] = og * tanhf(cn);
      int b = bbase + w * 16 + rbase + r;
      hb[((t + 1) & 1) * 65536 + b * 512 + hbase + hc] = f2bf(hv[r]);
    }
    // (f) per-wave release: orders THIS wave's h-stores (vmcnt drain + L2 wb),
    //     no block-wide fence needed. Group target: 32 blocks x 4 waves = 128/step.
    if (lane == 0)
      __hip_atomic_fetch_add(myctr, 1, __ATOMIC_RELEASE, __HIP_MEMORY_SCOPE_AGENT);
    // (g) out stores AFTER the release — off the inter-block critical path
#pragma unroll
    for (int r = 0; r < 4; ++r) {
      int b = bbase + w * 16 + rbase + r;
      out[(size_t)b * 262144 + (size_t)t * 512 + hbase + hc] = hv[r];
    }
  }
}

// ---------------- host ----------------
extern "C" void kernel_launch(void* const* d_in, const int* in_sizes, int n_in,
                              void* d_out, int out_size, void* d_ws, size_t ws_size,
                              hipStream_t stream) {
  const float* x = (const float*)d_in[0];
  const float* Wg[4] = {(const float*)d_in[1], (const float*)d_in[4],
                        (const float*)d_in[7], (const float*)d_in[10]};
  const float* Ug[4] = {(const float*)d_in[2], (const float*)d_in[5],
                        (const float*)d_in[8], (const float*)d_in[11]};
  const float* bg[4] = {(const float*)d_in[3], (const float*)d_in[6],
                        (const float*)d_in[9], (const float*)d_in[12]};
  float* out = (float*)d_out;
  char* ws = (char*)d_ws;

  // ws layout (all offsets 16B-aligned)
  int* ctr = (int*)ws;                                     // 1 KB (2 padded counters)
  short* hb = (short*)(ws + 1024);                         // 256 KB (h double-buffer)
  short* xb = (short*)(ws + 263168);                       // 32 MB
  short* wt = (short*)(ws + 263168 + 33554432ull);         // 1 MB
  short* ut = (short*)(ws + 263168 + 33554432ull + 1048576ull);  // 2 MB
  const size_t base = 263168ull + 33554432ull + 1048576ull + 2097152ull;  // 36,963,328
  short* gx = (short*)(ws + base);                         // 256 MB bf16 Gx

  if (ws_size < base + 268435456ull) return;  // ws too small -> d_out stays poisoned

  hipMemsetAsync(ws, 0, 263168, stream);      // counters + h double-buffer
  k_cvt_x<<<16384, 256, 0, stream>>>(x, xb);
  k_cvt_wu<<<dim3(1024, 8), 256, 0, stream>>>(Wg[0], Wg[1], Wg[2], Wg[3],
                                              Ug[0], Ug[1], Ug[2], Ug[3], wt, ut);
  k_gemm_x<<<8192, 256, 0, stream>>>(xb, wt, bg[0], bg[1], bg[2], bg[3], gx);
  hipFuncSetAttribute(reinterpret_cast<const void*>(&k_lstm),
                      hipFuncAttributeMaxDynamicSharedMemorySize, 65536);
  k_lstm<<<64, 256, 65536, stream>>>(ut, gx, hb, ctr, out);
}